// Round 3
// baseline (1070.436 us; speedup 1.0000x reference)
//
#include <hip/hip_runtime.h>

typedef unsigned short u16;
typedef unsigned int u32;

#define DEV static __device__ __forceinline__

DEV float bf2f(u16 v) { return __uint_as_float((u32)v << 16); }
DEV u16 f2bf(float f) {
    u32 x = __float_as_uint(f);
    return (u16)((x + 0x7fffu + ((x >> 16) & 1u)) >> 16);  // RNE
}

constexpr int Bn = 8, Tn = 2048, Fn = 80, NF = 64;
constexpr int H1 = 1024, W1n = 40;          // after conv0 (stride 2)
constexpr int Sn = 512,  W2n = 20;          // after conv1 (stride 2)
constexpr int PK = 1280;                    // 20*64
constexpr int I0 = 96;                      // 32 capsules * window 3
constexpr int O0 = 32;                      // conv capsules
constexpr int O1 = 31;                      // class capsules

// ---------------------------------------------------------------- block reduce
DEV float2 block_sum2(float a, float b, int tid, float* lds /*>=8 floats*/) {
    #pragma unroll
    for (int m = 1; m < 64; m <<= 1) {
        a += __shfl_xor(a, m);
        b += __shfl_xor(b, m);
    }
    int wid = tid >> 6;
    __syncthreads();
    if ((tid & 63) == 0) { lds[wid * 2] = a; lds[wid * 2 + 1] = b; }
    __syncthreads();
    float ra = lds[0] + lds[2] + lds[4] + lds[6];
    float rb = lds[1] + lds[3] + lds[5] + lds[7];
    return make_float2(ra, rb);
}

// ---------------------------------------------------------------- K1: conv0 maxout
// in [8,2048,80] f32 -> x1 [8,1024,40,64] bf16 (masked rows >= ceil(len/2) zeroed)
__global__ void __launch_bounds__(256) k_conv0(
        const float* __restrict__ in,
        const float* __restrict__ w1, const float* __restrict__ b1,
        const float* __restrict__ w2, const float* __restrict__ b2,
        const int* __restrict__ lens, u16* __restrict__ x1) {
    int idx = blockIdx.x * 256 + threadIdx.x;
    if (idx >= Bn * H1 * W1n * NF) return;
    int c = idx & 63;
    int rest = idx >> 6;
    int w = rest % W1n; rest /= W1n;
    int h = rest % H1;
    int b = rest / H1;
    float out = 0.f;
    int vl2 = (lens[b] + 1) >> 1;
    if (h < vl2) {
        float a1 = b1[c], a2 = b2[c];
        #pragma unroll
        for (int r = 0; r < 3; ++r) {
            int t = 2 * h + r;
            if (t < Tn) {
                #pragma unroll
                for (int q = 0; q < 3; ++q) {
                    int f = 2 * w + q;
                    if (f < Fn) {
                        float v = in[(b * Tn + t) * Fn + f];
                        int wi = (r * 3 + q) * 64 + c;
                        a1 = fmaf(v, w1[wi], a1);
                        a2 = fmaf(v, w2[wi], a2);
                    }
                }
            }
        }
        out = fmaxf(a1, a2);
    }
    x1[idx] = f2bf(out);
}

// ---------------------------------------------------------------- K2: conv1 maxout
// x1 [8,1024,40,64] bf16 -> x2 [8,512,20,64] f32 (masked rows >= ceil(len/4) zeroed)
// one block per (b,h); thread = (wq=tid/64, c=tid%64) computes 5 w positions
__global__ void __launch_bounds__(256) k_conv1(
        const u16* __restrict__ x1,
        const float* __restrict__ w1, const float* __restrict__ b1,
        const float* __restrict__ w2, const float* __restrict__ b2,
        const int* __restrict__ lens, float* __restrict__ x2) {
    __shared__ float patch[3 * 41 * 64];   // 31.5 KB
    int blk = blockIdx.x;
    int h = blk & (Sn - 1);
    int b = blk >> 9;
    int tid = threadIdx.x;

    for (int i = tid; i < 3 * 41 * 64; i += 256) {
        int ci  = i & 63;
        int col = (i >> 6) % 41;
        int r   = (i >> 6) / 41;
        int t = 2 * h + r;
        float v = 0.f;
        if (t < H1 && col < W1n)
            v = bf2f(x1[((b * H1 + t) * W1n + col) * 64 + ci]);
        patch[i] = v;
    }
    __syncthreads();

    int c = tid & 63;
    int wq = tid >> 6;                      // 0..3, each owns w = wq*5 .. wq*5+4
    float acc1[5], acc2[5];
    float bb1 = b1[c], bb2 = b2[c];
    #pragma unroll
    for (int p = 0; p < 5; ++p) { acc1[p] = bb1; acc2[p] = bb2; }

    #pragma unroll
    for (int r = 0; r < 3; ++r) {
        #pragma unroll
        for (int q = 0; q < 3; ++q) {
            // output w = wq*5 + p reads input col 2*w + q = 10*wq + 2*p + q
            int colbase = 10 * wq + q;
            const float* pp = &patch[(r * 41 + colbase) * 64];
            const float* wp1 = &w1[((r * 3 + q) * 64) * 64 + c];
            const float* wp2 = &w2[((r * 3 + q) * 64) * 64 + c];
            #pragma unroll 4
            for (int ci = 0; ci < 64; ++ci) {
                float wv1 = wp1[ci * 64];
                float wv2 = wp2[ci * 64];
                #pragma unroll
                for (int p = 0; p < 5; ++p) {
                    float x = pp[p * 128 + ci];
                    acc1[p] = fmaf(x, wv1, acc1[p]);
                    acc2[p] = fmaf(x, wv2, acc2[p]);
                }
            }
        }
    }
    int vl4 = (lens[b] + 3) >> 2;
    bool masked = (h >= vl4);
    #pragma unroll
    for (int p = 0; p < 5; ++p) {
        int w = wq * 5 + p;
        float o = masked ? 0.f : fmaxf(acc1[p], acc2[p]);
        x2[((b * Sn + h) * W2n + w) * 64 + c] = o;
    }
}

// ---------------------------------------------------------------- K3a: projection
// x2 [B*S,1280] f32 @ proj_w [1280,32] f32 + pb -> proj [B*S,32] f32
__global__ void __launch_bounds__(256) k_proj(
        const float* __restrict__ x2, const float* __restrict__ pw,
        const float* __restrict__ pb, float* __restrict__ proj) {
    int bs = blockIdx.x;
    int tid = threadIdx.x;
    int o = tid & 31, part = tid >> 5;      // 8 parts of 160
    const float* row = &x2[(size_t)bs * PK];
    float acc = 0.f;
    int k0 = part * 160;
    #pragma unroll 8
    for (int k = 0; k < 160; ++k)
        acc = fmaf(row[k0 + k], pw[(k0 + k) * 32 + o], acc);
    __shared__ float red[256];
    red[tid] = acc;
    __syncthreads();
    if (tid < 32) {
        float s = 0.f;
        #pragma unroll
        for (int p = 0; p < 8; ++p) s += red[p * 32 + tid];
        proj[bs * 32 + tid] = s + pb[tid];
    }
}

// ---------------------------------------------------------------- K3b: enc conv + mask + squash + LN
// proj [B,S,32] f32 -> emb0 [B,S,32,8] f32
__global__ void __launch_bounds__(256) k_enc(
        const float* __restrict__ proj,
        const float* __restrict__ ew1, const float* __restrict__ eb1,
        const float* __restrict__ ew2, const float* __restrict__ eb2,
        const int* __restrict__ lens, float* __restrict__ emb0) {
    int bs = blockIdx.x;
    int s = bs & (Sn - 1);
    int b = bs >> 9;
    int tid = threadIdx.x;
    __shared__ float rows[3][32];
    __shared__ float red[8];
    if (tid < 96) {
        int r = tid >> 5, n = tid & 31;
        int sr = s - 1 + r;
        rows[r][n] = (sr >= 0 && sr < Sn) ? proj[(b * Sn + sr) * 32 + n] : 0.f;
    }
    __syncthreads();

    int n = tid >> 3, d = tid & 7;
    float a1 = eb1[d], a2 = eb2[d];
    #pragma unroll
    for (int r = 0; r < 3; ++r) {
        #pragma unroll
        for (int q = 0; q < 3; ++q) {
            int nn = n - 1 + q;
            if (nn >= 0 && nn < 32) {
                float v = rows[r][nn];
                int wi = (r * 3 + q) * 8 + d;
                a1 = fmaf(v, ew1[wi], a1);
                a2 = fmaf(v, ew2[wi], a2);
            }
        }
    }
    float x = fmaxf(a1, a2);
    int vl4 = (lens[b] + 3) >> 2;
    if (s >= vl4) x = 0.f;

    // squash over d (aligned 8-lane groups)
    float sq = x * x;
    sq += __shfl_xor(sq, 1);
    sq += __shfl_xor(sq, 2);
    sq += __shfl_xor(sq, 4);
    x = x * (sq / (1.f + sq) * rsqrtf(sq + 1e-6f));

    // layernorm over 256
    float2 ss = block_sum2(x, x * x, tid, red);
    float mu = ss.x * (1.f / 256.f);
    float var = ss.y * (1.f / 256.f) - mu * mu;
    emb0[bs * 256 + tid] = (x - mu) * rsqrtf(var + 1e-3f);
}

// ---------------------------------------------------------------- K4: caps layer 0
// emb0 [B,S,32,8] -> routing -> LN -> emb1 [B,S,32,8]
// one block per (b,s); thread = (o=tid/8, d=tid%8); u_hat[i] in registers
__global__ void __launch_bounds__(256) k_caps0(
        const float* __restrict__ embin, const float* __restrict__ W0,
        const float* __restrict__ B0, float* __restrict__ embout) {
    int bs = blockIdx.x;
    int s = bs & (Sn - 1);
    int b = bs >> 9;
    int tid = threadIdx.x;
    int o = tid >> 3;

    __shared__ __align__(16) float win[I0 * 8];   // [i][k]
    __shared__ float blog[I0 * 33];               // stride 33: bank-conflict-free row scans
    __shared__ float cct[O0 * I0];                // transposed couplings [o][i]
    __shared__ float red[8];

    for (int i = tid; i < I0 * 8; i += 256) {
        int wj = i >> 8;                          // window slot 0..2
        int sr = s + wj - 1;
        win[i] = (sr >= 0 && sr < Sn) ? embin[(b * Sn + sr) * 256 + (i & 255)] : 0.f;
    }
    for (int i = tid; i < I0 * 33; i += 256) blog[i] = 0.f;
    __syncthreads();

    // u_hat: u[i] = B0[i,o,d] + sum_k W0[i,o,d,k] * win[i,k]
    // W0 flat index: i*2048 + tid*8 + k
    float u_reg[I0];
    {
        const float4* Wv = (const float4*)(W0 + tid * 8);
        const float4* w4 = (const float4*)win;
        #pragma unroll
        for (int i = 0; i < I0; ++i) {
            float4 va = Wv[i * 512], vb = Wv[i * 512 + 1];
            float4 wa = w4[i * 2], wb = w4[i * 2 + 1];
            float acc = B0[i * 256 + tid];
            acc = fmaf(va.x, wa.x, acc);
            acc = fmaf(va.y, wa.y, acc);
            acc = fmaf(va.z, wa.z, acc);
            acc = fmaf(va.w, wa.w, acc);
            acc = fmaf(vb.x, wb.x, acc);
            acc = fmaf(vb.y, wb.y, acc);
            acc = fmaf(vb.z, wb.z, acc);
            acc = fmaf(vb.w, wb.w, acc);
            u_reg[i] = acc;
        }
    }

    float vval = 0.f;
    for (int it = 0; it < 3; ++it) {
        // softmax over o per input capsule i (threads 0..95)
        if (tid < I0) {
            float m = -1e30f;
            for (int oo = 0; oo < O0; ++oo) m = fmaxf(m, blog[tid * 33 + oo]);
            float ssum = 0.f;
            for (int oo = 0; oo < O0; ++oo) ssum += __expf(blog[tid * 33 + oo] - m);
            float inv = 1.f / ssum;
            for (int oo = 0; oo < O0; ++oo)
                cct[oo * I0 + tid] = __expf(blog[tid * 33 + oo] - m) * inv;
        }
        __syncthreads();
        // s[o,d] = sum_i c[i,o] * u[i,o,d]
        float sv = 0.f;
        {
            const float* cr = &cct[o * I0];
            #pragma unroll
            for (int i = 0; i < I0; ++i) sv = fmaf(cr[i], u_reg[i], sv);
        }
        // squash over d
        float sq = sv * sv;
        sq += __shfl_xor(sq, 1);
        sq += __shfl_xor(sq, 2);
        sq += __shfl_xor(sq, 4);
        vval = sv * (sq / (1.f + sq) * rsqrtf(sq + 1e-6f));
        if (it < 2) {
            // b[i,o] += sum_d u[i,o,d] * v[o,d]
            #pragma unroll
            for (int i = 0; i < I0; ++i) {
                float p = u_reg[i] * vval;
                p += __shfl_xor(p, 1);
                p += __shfl_xor(p, 2);
                p += __shfl_xor(p, 4);
                if ((tid & 7) == 0) blog[i * 33 + o] += p;
            }
            __syncthreads();
        }
    }

    // layernorm over 256 and write
    float2 ss = block_sum2(vval, vval * vval, tid, red);
    float mu = ss.x * (1.f / 256.f);
    float var = ss.y * (1.f / 256.f) - mu * mu;
    embout[bs * 256 + tid] = (vval - mu) * rsqrtf(var + 1e-3f);
}

// ---------------------------------------------------------------- K5: caps layer 1 + epilogue
// emb1 -> routing(31 classes, class0 masked) -> LN(248) -> lengths -> LN(31) -> out f32
__global__ void __launch_bounds__(256) k_caps1(
        const float* __restrict__ embin, const float* __restrict__ W1,
        const float* __restrict__ B1, float* __restrict__ outp) {
    int bs = blockIdx.x;
    int s = bs & (Sn - 1);
    int b = bs >> 9;
    int tid = threadIdx.x;
    int o = tid >> 3, d = tid & 7;
    bool valid = (o < O1);
    int oc = valid ? o : (O1 - 1);

    __shared__ __align__(16) float win[I0 * 8];
    __shared__ float blog[I0 * 33];
    __shared__ float cct[O1 * I0];
    __shared__ float red[8];
    __shared__ float lenb[O1];
    __shared__ float mv2[2];

    for (int i = tid; i < I0 * 8; i += 256) {
        int wj = i >> 8;
        int sr = s + wj - 1;
        win[i] = (sr >= 0 && sr < Sn) ? embin[(b * Sn + sr) * 256 + (i & 255)] : 0.f;
    }
    for (int i = tid; i < I0 * 33; i += 256) blog[i] = 0.f;
    __syncthreads();

    // W1 flat index: i*1984 + (oc*8+d)*8 + k
    float u_reg[I0];
    {
        const float4* Wv = (const float4*)(W1 + (oc * 8 + d) * 8);
        const float4* w4 = (const float4*)win;
        #pragma unroll
        for (int i = 0; i < I0; ++i) {
            float4 va = Wv[i * 496], vb = Wv[i * 496 + 1];
            float4 wa = w4[i * 2], wb = w4[i * 2 + 1];
            float acc = B1[i * 248 + oc * 8 + d];
            acc = fmaf(va.x, wa.x, acc);
            acc = fmaf(va.y, wa.y, acc);
            acc = fmaf(va.z, wa.z, acc);
            acc = fmaf(va.w, wa.w, acc);
            acc = fmaf(vb.x, wb.x, acc);
            acc = fmaf(vb.y, wb.y, acc);
            acc = fmaf(vb.z, wb.z, acc);
            acc = fmaf(vb.w, wb.w, acc);
            u_reg[i] = acc;
        }
    }

    float vval = 0.f;
    for (int it = 0; it < 3; ++it) {
        if (tid < I0) {
            float m = -1e30f;
            for (int oo = 0; oo < O1; ++oo) {
                float lv = blog[tid * 33 + oo] + (oo == 0 ? -1e9f : 0.f);
                m = fmaxf(m, lv);
            }
            float ssum = 0.f;
            for (int oo = 0; oo < O1; ++oo) {
                float lv = blog[tid * 33 + oo] + (oo == 0 ? -1e9f : 0.f);
                ssum += __expf(lv - m);
            }
            float inv = 1.f / ssum;
            for (int oo = 0; oo < O1; ++oo) {
                float lv = blog[tid * 33 + oo] + (oo == 0 ? -1e9f : 0.f);
                cct[oo * I0 + tid] = __expf(lv - m) * inv;
            }
        }
        __syncthreads();
        float sv = 0.f;
        {
            const float* cr = &cct[oc * I0];
            #pragma unroll
            for (int i = 0; i < I0; ++i) sv = fmaf(cr[i], u_reg[i], sv);
        }
        float sq = sv * sv;
        sq += __shfl_xor(sq, 1);
        sq += __shfl_xor(sq, 2);
        sq += __shfl_xor(sq, 4);
        vval = sv * (sq / (1.f + sq) * rsqrtf(sq + 1e-6f));
        if (!valid) vval = 0.f;
        if (it < 2) {
            #pragma unroll
            for (int i = 0; i < I0; ++i) {
                float p = u_reg[i] * vval;
                p += __shfl_xor(p, 1);
                p += __shfl_xor(p, 2);
                p += __shfl_xor(p, 4);
                if ((tid & 7) == 0 && valid) blog[i * 33 + o] += p;
            }
            __syncthreads();
        }
    }

    // layernorm over 248
    float2 ss = block_sum2(vval, vval * vval, tid, red);
    float mu = ss.x * (1.f / 248.f);
    float var = ss.y * (1.f / 248.f) - mu * mu;
    float y = (vval - mu) * rsqrtf(var + 1e-3f);

    // capsule lengths
    float sq = y * y;
    sq += __shfl_xor(sq, 1);
    sq += __shfl_xor(sq, 2);
    sq += __shfl_xor(sq, 4);
    if (valid && (tid & 7) == 0) lenb[o] = sqrtf(sq + 1e-6f);
    __syncthreads();

    // final layernorm over 31
    if (tid == 0) {
        float s1 = 0.f, s2 = 0.f;
        for (int oo = 0; oo < O1; ++oo) { float t = lenb[oo]; s1 += t; s2 += t * t; }
        float m2 = s1 / 31.f;
        mv2[0] = m2;
        mv2[1] = rsqrtf(s2 / 31.f - m2 * m2 + 1e-3f);
    }
    __syncthreads();
    if (tid < O1)
        outp[(size_t)bs * O1 + tid] = (lenb[tid] - mv2[0]) * mv2[1];
}

// ---------------------------------------------------------------- launch
extern "C" void kernel_launch(void* const* d_in, const int* in_sizes, int n_in,
                              void* d_out, int out_size, void* d_ws, size_t ws_size,
                              hipStream_t stream) {
    const float* inputs = (const float*)d_in[0];
    const float* c0w1 = (const float*)d_in[1];
    const float* c0b1 = (const float*)d_in[2];
    const float* c0w2 = (const float*)d_in[3];
    const float* c0b2 = (const float*)d_in[4];
    const float* c1w1 = (const float*)d_in[5];
    const float* c1b1 = (const float*)d_in[6];
    const float* c1w2 = (const float*)d_in[7];
    const float* c1b2 = (const float*)d_in[8];
    const float* pw   = (const float*)d_in[9];
    const float* pb   = (const float*)d_in[10];
    const float* ew1  = (const float*)d_in[11];
    const float* eb1  = (const float*)d_in[12];
    const float* ew2  = (const float*)d_in[13];
    const float* eb2  = (const float*)d_in[14];
    const float* W0   = (const float*)d_in[15];
    const float* B0   = (const float*)d_in[16];
    const float* W1   = (const float*)d_in[17];
    const float* B1   = (const float*)d_in[18];
    const int* lens = (const int*)d_in[19];

    char* ws = (char*)d_ws;
    u16*   x1   = (u16*)(ws);                        // 41,943,040 B
    float* x2   = (float*)(ws + 41943040);           // 20,971,520 B
    float* proj = (float*)(ws + 62914560);           //    524,288 B
    float* emb0 = (float*)(ws + 63438848);           //  4,194,304 B
    float* emb1 = (float*)(ws + 67633152);           //  4,194,304 B  (end ~71.8 MB)

    k_conv0<<<(Bn * H1 * W1n * NF) / 256, 256, 0, stream>>>(
        inputs, c0w1, c0b1, c0w2, c0b2, lens, x1);
    k_conv1<<<Bn * Sn, 256, 0, stream>>>(x1, c1w1, c1b1, c1w2, c1b2, lens, x2);
    k_proj<<<Bn * Sn, 256, 0, stream>>>(x2, pw, pb, proj);
    k_enc<<<Bn * Sn, 256, 0, stream>>>(proj, ew1, eb1, ew2, eb2, lens, emb0);
    k_caps0<<<Bn * Sn, 256, 0, stream>>>(emb0, W0, B0, emb1);
    k_caps1<<<Bn * Sn, 256, 0, stream>>>(emb1, W1, B1, (float*)d_out);
}

// Round 4
// 771.078 us; speedup vs baseline: 1.3882x; 1.3882x over previous
//
#include <hip/hip_runtime.h>

typedef unsigned short u16;
typedef unsigned int u32;

#define DEV static __device__ __forceinline__

DEV float bf2f(u16 v) { return __uint_as_float((u32)v << 16); }
DEV u16 f2bf(float f) {
    u32 x = __float_as_uint(f);
    return (u16)((x + 0x7fffu + ((x >> 16) & 1u)) >> 16);  // RNE
}

constexpr int Bn = 8, Tn = 2048, Fn = 80, NF = 64;
constexpr int H1 = 1024, W1n = 40;          // after conv0 (stride 2)
constexpr int Sn = 512,  W2n = 20;          // after conv1 (stride 2)
constexpr int PK = 1280;                    // 20*64
constexpr int I0 = 96;                      // 32 capsules * window 3
constexpr int O0 = 32;                      // conv capsules
constexpr int O1 = 31;                      // class capsules
constexpr int CP = 97;                      // cct row stride (97%32=1 -> conflict-free)
constexpr int NW0 = I0 * O0 * 8 * 8;        // 196608
constexpr int NW1 = I0 * O1 * 8 * 8;        // 190464

// ---------------------------------------------------------------- DPP 8-lane allreduce (sum)
template <int CTRL>
DEV float dpp_mov(float x) {
    return __int_as_float(__builtin_amdgcn_update_dpp(
        0, __float_as_int(x), CTRL, 0xF, 0xF, true));
}
DEV float sum8(float x) {
    // 8-lane groups are lane-aligned (tid%8 = d). xor1, xor2 via quad_perm,
    // then row_half_mirror folds the two quads -> full 8-sum in all 8 lanes.
    x += dpp_mov<0xB1>(x);    // quad_perm [1,0,3,2]
    x += dpp_mov<0x4E>(x);    // quad_perm [2,3,0,1]
    x += dpp_mov<0x141>(x);   // row_half_mirror
    return x;
}

// ---------------------------------------------------------------- block reduce
DEV float2 block_sum2(float a, float b, int tid, float* lds /*>=8 floats*/) {
    #pragma unroll
    for (int m = 1; m < 64; m <<= 1) {
        a += __shfl_xor(a, m);
        b += __shfl_xor(b, m);
    }
    int wid = tid >> 6;
    __syncthreads();
    if ((tid & 63) == 0) { lds[wid * 2] = a; lds[wid * 2 + 1] = b; }
    __syncthreads();
    float ra = lds[0] + lds[2] + lds[4] + lds[6];
    float rb = lds[1] + lds[3] + lds[5] + lds[7];
    return make_float2(ra, rb);
}

// ---------------------------------------------------------------- K0: W -> bf16 staging
__global__ void __launch_bounds__(256) k_cvtw(
        const float* __restrict__ w0, const float* __restrict__ w1,
        u16* __restrict__ w0b, u16* __restrict__ w1b) {
    int idx = blockIdx.x * 256 + threadIdx.x;
    if (idx < NW0) w0b[idx] = f2bf(w0[idx]);
    if (idx < NW1) w1b[idx] = f2bf(w1[idx]);
}

// ---------------------------------------------------------------- K1: conv0 maxout
__global__ void __launch_bounds__(256) k_conv0(
        const float* __restrict__ in,
        const float* __restrict__ w1, const float* __restrict__ b1,
        const float* __restrict__ w2, const float* __restrict__ b2,
        const int* __restrict__ lens, u16* __restrict__ x1) {
    int idx = blockIdx.x * 256 + threadIdx.x;
    if (idx >= Bn * H1 * W1n * NF) return;
    int c = idx & 63;
    int rest = idx >> 6;
    int w = rest % W1n; rest /= W1n;
    int h = rest % H1;
    int b = rest / H1;
    float out = 0.f;
    int vl2 = (lens[b] + 1) >> 1;
    if (h < vl2) {
        float a1 = b1[c], a2 = b2[c];
        #pragma unroll
        for (int r = 0; r < 3; ++r) {
            int t = 2 * h + r;
            if (t < Tn) {
                #pragma unroll
                for (int q = 0; q < 3; ++q) {
                    int f = 2 * w + q;
                    if (f < Fn) {
                        float v = in[(b * Tn + t) * Fn + f];
                        int wi = (r * 3 + q) * 64 + c;
                        a1 = fmaf(v, w1[wi], a1);
                        a2 = fmaf(v, w2[wi], a2);
                    }
                }
            }
        }
        out = fmaxf(a1, a2);
    }
    x1[idx] = f2bf(out);
}

// ---------------------------------------------------------------- K2: conv1 maxout
__global__ void __launch_bounds__(256) k_conv1(
        const u16* __restrict__ x1,
        const float* __restrict__ w1, const float* __restrict__ b1,
        const float* __restrict__ w2, const float* __restrict__ b2,
        const int* __restrict__ lens, u16* __restrict__ x2) {
    __shared__ float patch[3 * 41 * 64];   // 31.5 KB
    int blk = blockIdx.x;
    int h = blk & (Sn - 1);
    int b = blk >> 9;
    int tid = threadIdx.x;

    for (int i = tid; i < 3 * 41 * 64; i += 256) {
        int ci  = i & 63;
        int col = (i >> 6) % 41;
        int r   = (i >> 6) / 41;
        int t = 2 * h + r;
        float v = 0.f;
        if (t < H1 && col < W1n)
            v = bf2f(x1[((b * H1 + t) * W1n + col) * 64 + ci]);
        patch[i] = v;
    }
    __syncthreads();

    int c = tid & 63;
    int wq = tid >> 6;                      // 0..3, each owns w = wq*5 .. wq*5+4
    float acc1[5], acc2[5];
    float bb1 = b1[c], bb2 = b2[c];
    #pragma unroll
    for (int p = 0; p < 5; ++p) { acc1[p] = bb1; acc2[p] = bb2; }

    #pragma unroll
    for (int r = 0; r < 3; ++r) {
        #pragma unroll
        for (int q = 0; q < 3; ++q) {
            // output w = wq*5 + p reads input col 2*w + q = 10*wq + 2*p + q
            int colbase = 10 * wq + q;
            const float* pp = &patch[(r * 41 + colbase) * 64];
            const float* wp1 = &w1[((r * 3 + q) * 64) * 64 + c];
            const float* wp2 = &w2[((r * 3 + q) * 64) * 64 + c];
            #pragma unroll 4
            for (int ci = 0; ci < 64; ++ci) {
                float wv1 = wp1[ci * 64];
                float wv2 = wp2[ci * 64];
                #pragma unroll
                for (int p = 0; p < 5; ++p) {
                    float x = pp[p * 128 + ci];
                    acc1[p] = fmaf(x, wv1, acc1[p]);
                    acc2[p] = fmaf(x, wv2, acc2[p]);
                }
            }
        }
    }
    int vl4 = (lens[b] + 3) >> 2;
    bool masked = (h >= vl4);
    #pragma unroll
    for (int p = 0; p < 5; ++p) {
        int w = wq * 5 + p;
        float o = masked ? 0.f : fmaxf(acc1[p], acc2[p]);
        x2[((b * Sn + h) * W2n + w) * 64 + c] = f2bf(o);
    }
}

// ---------------------------------------------------------------- K3a: projection
// x2 [B*S,1280] bf16 @ proj_w [1280,32] f32 + pb -> proj [B*S,32] f32
__global__ void __launch_bounds__(256) k_proj(
        const u16* __restrict__ x2, const float* __restrict__ pw,
        const float* __restrict__ pb, float* __restrict__ proj) {
    int bs = blockIdx.x;
    int tid = threadIdx.x;
    int o = tid & 31, part = tid >> 5;      // 8 parts of 160
    const u16* row = &x2[(size_t)bs * PK];
    float acc = 0.f;
    int k0 = part * 160;
    #pragma unroll 8
    for (int k = 0; k < 160; ++k)
        acc = fmaf(bf2f(row[k0 + k]), pw[(k0 + k) * 32 + o], acc);
    __shared__ float red[256];
    red[tid] = acc;
    __syncthreads();
    if (tid < 32) {
        float s = 0.f;
        #pragma unroll
        for (int p = 0; p < 8; ++p) s += red[p * 32 + tid];
        proj[bs * 32 + tid] = s + pb[tid];
    }
}

// ---------------------------------------------------------------- K3b: enc conv + mask + squash + LN
__global__ void __launch_bounds__(256) k_enc(
        const float* __restrict__ proj,
        const float* __restrict__ ew1, const float* __restrict__ eb1,
        const float* __restrict__ ew2, const float* __restrict__ eb2,
        const int* __restrict__ lens, float* __restrict__ emb0) {
    int bs = blockIdx.x;
    int s = bs & (Sn - 1);
    int b = bs >> 9;
    int tid = threadIdx.x;
    __shared__ float rows[3][32];
    __shared__ float red[8];
    if (tid < 96) {
        int r = tid >> 5, n = tid & 31;
        int sr = s - 1 + r;
        rows[r][n] = (sr >= 0 && sr < Sn) ? proj[(b * Sn + sr) * 32 + n] : 0.f;
    }
    __syncthreads();

    int n = tid >> 3, d = tid & 7;
    float a1 = eb1[d], a2 = eb2[d];
    #pragma unroll
    for (int r = 0; r < 3; ++r) {
        #pragma unroll
        for (int q = 0; q < 3; ++q) {
            int nn = n - 1 + q;
            if (nn >= 0 && nn < 32) {
                float v = rows[r][nn];
                int wi = (r * 3 + q) * 8 + d;
                a1 = fmaf(v, ew1[wi], a1);
                a2 = fmaf(v, ew2[wi], a2);
            }
        }
    }
    float x = fmaxf(a1, a2);
    int vl4 = (lens[b] + 3) >> 2;
    if (s >= vl4) x = 0.f;

    // squash over d
    float sq = sum8(x * x);
    x = x * (sq / (1.f + sq) * rsqrtf(sq + 1e-6f));

    // layernorm over 256
    float2 ss = block_sum2(x, x * x, tid, red);
    float mu = ss.x * (1.f / 256.f);
    float var = ss.y * (1.f / 256.f) - mu * mu;
    emb0[bs * 256 + tid] = (x - mu) * rsqrtf(var + 1e-3f);
}

// ---------------------------------------------------------------- K4: caps layer 0
__global__ void __launch_bounds__(256) k_caps0(
        const float* __restrict__ embin, const u16* __restrict__ W0,
        const float* __restrict__ B0, float* __restrict__ embout) {
    int bs = blockIdx.x;
    int s = bs & (Sn - 1);
    int b = bs >> 9;
    int tid = threadIdx.x;
    int o = tid >> 3;

    __shared__ __align__(16) float win[I0 * 8];   // [i][k]
    __shared__ float blog[I0 * 33];               // (i+o)%32 banks: conflict-free
    __shared__ float cct[O0 * CP];                // [o][i] stride 97: conflict-free
    __shared__ float red[8];

    for (int i = tid; i < I0 * 8; i += 256) {
        int wj = i >> 8;                          // window slot 0..2
        int sr = s + wj - 1;
        win[i] = (sr >= 0 && sr < Sn) ? embin[(b * Sn + sr) * 256 + (i & 255)] : 0.f;
    }
    for (int i = tid; i < I0 * 33; i += 256) blog[i] = 0.f;
    __syncthreads();

    // u_hat: u[i] = B0[i,o,d] + sum_k W0[i,o,d,k] * win[i,k]  (W0 bf16-staged)
    float u_reg[I0];
    {
        const uint4* Wv = (const uint4*)W0;       // 16 B = 8 bf16 per (i,o,d)
        const float4* w4 = (const float4*)win;
        #pragma unroll
        for (int i = 0; i < I0; ++i) {
            uint4 wv = Wv[i * 256 + tid];
            float4 wa = w4[i * 2], wb = w4[i * 2 + 1];
            float acc = B0[i * 256 + tid];
            acc = fmaf(__uint_as_float(wv.x << 16),         wa.x, acc);
            acc = fmaf(__uint_as_float(wv.x & 0xffff0000u), wa.y, acc);
            acc = fmaf(__uint_as_float(wv.y << 16),         wa.z, acc);
            acc = fmaf(__uint_as_float(wv.y & 0xffff0000u), wa.w, acc);
            acc = fmaf(__uint_as_float(wv.z << 16),         wb.x, acc);
            acc = fmaf(__uint_as_float(wv.z & 0xffff0000u), wb.y, acc);
            acc = fmaf(__uint_as_float(wv.w << 16),         wb.z, acc);
            acc = fmaf(__uint_as_float(wv.w & 0xffff0000u), wb.w, acc);
            u_reg[i] = acc;
        }
    }

    float vval = 0.f;
    for (int it = 0; it < 3; ++it) {
        // softmax over o per input capsule i (threads 0..95)
        if (tid < I0) {
            float m = -1e30f;
            for (int oo = 0; oo < O0; ++oo) m = fmaxf(m, blog[tid * 33 + oo]);
            float ssum = 0.f;
            for (int oo = 0; oo < O0; ++oo) ssum += __expf(blog[tid * 33 + oo] - m);
            float inv = __builtin_amdgcn_rcpf(ssum);
            for (int oo = 0; oo < O0; ++oo)
                cct[oo * CP + tid] = __expf(blog[tid * 33 + oo] - m) * inv;
        }
        __syncthreads();
        // s[o,d] = sum_i c[i,o] * u[i,o,d]
        float sv = 0.f;
        {
            const float* cr = &cct[o * CP];
            #pragma unroll
            for (int i = 0; i < I0; ++i) sv = fmaf(cr[i], u_reg[i], sv);
        }
        // squash over d (DPP)
        float sq = sum8(sv * sv);
        vval = sv * (sq / (1.f + sq) * rsqrtf(sq + 1e-6f));
        if (it < 2) {
            // b[i,o] += sum_d u[i,o,d] * v[o,d]  (DPP 8-lane sum, no LDS pipe)
            #pragma unroll
            for (int i = 0; i < I0; ++i) {
                float p = sum8(u_reg[i] * vval);
                if ((tid & 7) == 0) blog[i * 33 + o] += p;
            }
            __syncthreads();
        }
    }

    // layernorm over 256 and write
    float2 ss = block_sum2(vval, vval * vval, tid, red);
    float mu = ss.x * (1.f / 256.f);
    float var = ss.y * (1.f / 256.f) - mu * mu;
    embout[bs * 256 + tid] = (vval - mu) * rsqrtf(var + 1e-3f);
}

// ---------------------------------------------------------------- K5: caps layer 1 + epilogue
__global__ void __launch_bounds__(256) k_caps1(
        const float* __restrict__ embin, const u16* __restrict__ W1,
        const float* __restrict__ B1, float* __restrict__ outp) {
    int bs = blockIdx.x;
    int s = bs & (Sn - 1);
    int b = bs >> 9;
    int tid = threadIdx.x;
    int o = tid >> 3, d = tid & 7;
    bool valid = (o < O1);
    int oc = valid ? o : (O1 - 1);
    int ocd = oc * 8 + d;

    __shared__ __align__(16) float win[I0 * 8];
    __shared__ float blog[I0 * 33];
    __shared__ float cct[O1 * CP];
    __shared__ float red[8];
    __shared__ float lenb[O1];
    __shared__ float mv2[2];

    for (int i = tid; i < I0 * 8; i += 256) {
        int wj = i >> 8;
        int sr = s + wj - 1;
        win[i] = (sr >= 0 && sr < Sn) ? embin[(b * Sn + sr) * 256 + (i & 255)] : 0.f;
    }
    for (int i = tid; i < I0 * 33; i += 256) blog[i] = 0.f;
    __syncthreads();

    // u_hat (W1 bf16-staged); flat: i*1984 + ocd*8 + k -> uint4 idx i*248 + ocd
    float u_reg[I0];
    {
        const uint4* Wv = (const uint4*)W1;
        const float4* w4 = (const float4*)win;
        #pragma unroll
        for (int i = 0; i < I0; ++i) {
            uint4 wv = Wv[i * 248 + ocd];
            float4 wa = w4[i * 2], wb = w4[i * 2 + 1];
            float acc = B1[i * 248 + ocd];
            acc = fmaf(__uint_as_float(wv.x << 16),         wa.x, acc);
            acc = fmaf(__uint_as_float(wv.x & 0xffff0000u), wa.y, acc);
            acc = fmaf(__uint_as_float(wv.y << 16),         wa.z, acc);
            acc = fmaf(__uint_as_float(wv.y & 0xffff0000u), wa.w, acc);
            acc = fmaf(__uint_as_float(wv.z << 16),         wb.x, acc);
            acc = fmaf(__uint_as_float(wv.z & 0xffff0000u), wb.y, acc);
            acc = fmaf(__uint_as_float(wv.w << 16),         wb.z, acc);
            acc = fmaf(__uint_as_float(wv.w & 0xffff0000u), wb.w, acc);
            u_reg[i] = acc;
        }
    }

    float vval = 0.f;
    for (int it = 0; it < 3; ++it) {
        if (tid < I0) {
            float m = -1e30f;
            for (int oo = 0; oo < O1; ++oo) {
                float lv = blog[tid * 33 + oo] + (oo == 0 ? -1e9f : 0.f);
                m = fmaxf(m, lv);
            }
            float ssum = 0.f;
            for (int oo = 0; oo < O1; ++oo) {
                float lv = blog[tid * 33 + oo] + (oo == 0 ? -1e9f : 0.f);
                ssum += __expf(lv - m);
            }
            float inv = __builtin_amdgcn_rcpf(ssum);
            for (int oo = 0; oo < O1; ++oo) {
                float lv = blog[tid * 33 + oo] + (oo == 0 ? -1e9f : 0.f);
                cct[oo * CP + tid] = __expf(lv - m) * inv;
            }
        }
        __syncthreads();
        float sv = 0.f;
        {
            const float* cr = &cct[oc * CP];
            #pragma unroll
            for (int i = 0; i < I0; ++i) sv = fmaf(cr[i], u_reg[i], sv);
        }
        float sq = sum8(sv * sv);
        vval = sv * (sq / (1.f + sq) * rsqrtf(sq + 1e-6f));
        if (!valid) vval = 0.f;
        if (it < 2) {
            #pragma unroll
            for (int i = 0; i < I0; ++i) {
                float p = sum8(u_reg[i] * vval);
                if ((tid & 7) == 0 && valid) blog[i * 33 + o] += p;
            }
            __syncthreads();
        }
    }

    // layernorm over 248
    float2 ss = block_sum2(vval, vval * vval, tid, red);
    float mu = ss.x * (1.f / 248.f);
    float var = ss.y * (1.f / 248.f) - mu * mu;
    float y = (vval - mu) * rsqrtf(var + 1e-3f);

    // capsule lengths
    float sq = sum8(y * y);
    if (valid && (tid & 7) == 0) lenb[o] = sqrtf(sq + 1e-6f);
    __syncthreads();

    // final layernorm over 31
    if (tid == 0) {
        float s1 = 0.f, s2 = 0.f;
        for (int oo = 0; oo < O1; ++oo) { float t = lenb[oo]; s1 += t; s2 += t * t; }
        float m2 = s1 / 31.f;
        mv2[0] = m2;
        mv2[1] = rsqrtf(s2 / 31.f - m2 * m2 + 1e-3f);
    }
    __syncthreads();
    if (tid < O1)
        outp[(size_t)bs * O1 + tid] = (lenb[tid] - mv2[0]) * mv2[1];
}

// ---------------------------------------------------------------- launch
extern "C" void kernel_launch(void* const* d_in, const int* in_sizes, int n_in,
                              void* d_out, int out_size, void* d_ws, size_t ws_size,
                              hipStream_t stream) {
    const float* inputs = (const float*)d_in[0];
    const float* c0w1 = (const float*)d_in[1];
    const float* c0b1 = (const float*)d_in[2];
    const float* c0w2 = (const float*)d_in[3];
    const float* c0b2 = (const float*)d_in[4];
    const float* c1w1 = (const float*)d_in[5];
    const float* c1b1 = (const float*)d_in[6];
    const float* c1w2 = (const float*)d_in[7];
    const float* c1b2 = (const float*)d_in[8];
    const float* pw   = (const float*)d_in[9];
    const float* pb   = (const float*)d_in[10];
    const float* ew1  = (const float*)d_in[11];
    const float* eb1  = (const float*)d_in[12];
    const float* ew2  = (const float*)d_in[13];
    const float* eb2  = (const float*)d_in[14];
    const float* W0   = (const float*)d_in[15];
    const float* B0   = (const float*)d_in[16];
    const float* W1   = (const float*)d_in[17];
    const float* B1   = (const float*)d_in[18];
    const int* lens = (const int*)d_in[19];

    char* ws = (char*)d_ws;
    u16*   x1   = (u16*)(ws);                        // 41,943,040 B
    u16*   x2   = (u16*)(ws + 41943040);             // 10,485,760 B (bf16)
    float* proj = (float*)(ws + 52428800);           //    524,288 B
    float* emb0 = (float*)(ws + 52953088);           //  4,194,304 B
    float* emb1 = (float*)(ws + 57147392);           //  4,194,304 B
    u16*   W0b  = (u16*)(ws + 61341696);             //    393,216 B
    u16*   W1b  = (u16*)(ws + 61734912);             //    380,928 B  (end ~62.1 MB)

    k_cvtw<<<(NW0 + 255) / 256, 256, 0, stream>>>(W0, W1, W0b, W1b);
    k_conv0<<<(Bn * H1 * W1n * NF) / 256, 256, 0, stream>>>(
        inputs, c0w1, c0b1, c0w2, c0b2, lens, x1);
    k_conv1<<<Bn * Sn, 256, 0, stream>>>(x1, c1w1, c1b1, c1w2, c1b2, lens, x2);
    k_proj<<<Bn * Sn, 256, 0, stream>>>(x2, pw, pb, proj);
    k_enc<<<Bn * Sn, 256, 0, stream>>>(proj, ew1, eb1, ew2, eb2, lens, emb0);
    k_caps0<<<Bn * Sn, 256, 0, stream>>>(emb0, W0b, B0, emb1);
    k_caps1<<<Bn * Sn, 256, 0, stream>>>(emb1, W1b, B1, (float*)d_out);
}

// Round 5
// 580.635 us; speedup vs baseline: 1.8436x; 1.3280x over previous
//
#include <hip/hip_runtime.h>

typedef unsigned short u16;
typedef unsigned int u32;
typedef short short8 __attribute__((ext_vector_type(8)));
typedef float f32x4 __attribute__((ext_vector_type(4)));

#define DEV static __device__ __forceinline__

DEV float bf2f(u16 v) { return __uint_as_float((u32)v << 16); }
DEV u16 f2bf(float f) {
    u32 x = __float_as_uint(f);
    return (u16)((x + 0x7fffu + ((x >> 16) & 1u)) >> 16);  // RNE
}

constexpr int Bn = 8, Tn = 2048, Fn = 80, NF = 64;
constexpr int H1 = 1024, W1n = 40;          // after conv0 (stride 2)
constexpr int Sn = 512,  W2n = 20;          // after conv1 (stride 2)
constexpr int PK = 1280;                    // 20*64
constexpr int I0 = 96;                      // 32 capsules * window 3
constexpr int O0 = 32;                      // conv capsules
constexpr int O1 = 31;                      // class capsules
constexpr int CP = 97;                      // cct row stride (conflict-free)
constexpr int NW0 = I0 * O0 * 8 * 8;        // 196608
constexpr int NW1 = I0 * O1 * 8 * 8;        // 190464
constexpr int KC1 = 576;                    // conv1 GEMM K (9*64)

// ---------------------------------------------------------------- DPP helpers
template <int CTRL>
DEV float dpp_mov(float x) {
    return __int_as_float(__builtin_amdgcn_update_dpp(
        0, __float_as_int(x), CTRL, 0xF, 0xF, true));
}
DEV float sum8(float x) {
    x += dpp_mov<0xB1>(x);    // quad_perm xor1
    x += dpp_mov<0x4E>(x);    // quad_perm xor2
    x += dpp_mov<0x141>(x);   // row_half_mirror
    return x;
}

// ---------------------------------------------------------------- block reduce
DEV float2 block_sum2(float a, float b, int tid, float* lds /*>=8 floats*/) {
    #pragma unroll
    for (int m = 1; m < 64; m <<= 1) {
        a += __shfl_xor(a, m);
        b += __shfl_xor(b, m);
    }
    int wid = tid >> 6;
    __syncthreads();
    if ((tid & 63) == 0) { lds[wid * 2] = a; lds[wid * 2 + 1] = b; }
    __syncthreads();
    float ra = lds[0] + lds[2] + lds[4] + lds[6];
    float rb = lds[1] + lds[3] + lds[5] + lds[7];
    return make_float2(ra, rb);
}

// ---------------------------------------------------------------- K0: prep
// caps W -> bf16; conv1 weights -> wt[n'=2c+s][k] bf16 (+ interleaved bias)
__global__ void __launch_bounds__(256) k_prep(
        const float* __restrict__ w0, const float* __restrict__ w1c,
        const float* __restrict__ cw1, const float* __restrict__ cb1,
        const float* __restrict__ cw2, const float* __restrict__ cb2,
        u16* __restrict__ w0b, u16* __restrict__ w1b,
        u16* __restrict__ wt, float* __restrict__ biasi) {
    int idx = blockIdx.x * 256 + threadIdx.x;
    if (idx < NW0) w0b[idx] = f2bf(w0[idx]);
    if (idx < NW1) w1b[idx] = f2bf(w1c[idx]);
    if (idx < 128 * KC1) {
        int n = idx / KC1, k = idx - n * KC1;
        int c = n >> 1, s = n & 1;
        const float* w = s ? cw2 : cw1;   // [3,3,64,64] flat: k*64 + c
        wt[idx] = f2bf(w[k * 64 + c]);
    }
    if (idx < 128) {
        int c = idx >> 1, s = idx & 1;
        biasi[idx] = (s ? cb2 : cb1)[c];
    }
}

// ---------------------------------------------------------------- K1: conv0 maxout
__global__ void __launch_bounds__(256) k_conv0(
        const float* __restrict__ in,
        const float* __restrict__ w1, const float* __restrict__ b1,
        const float* __restrict__ w2, const float* __restrict__ b2,
        const int* __restrict__ lens, u16* __restrict__ x1) {
    int idx = blockIdx.x * 256 + threadIdx.x;
    if (idx >= Bn * H1 * W1n * NF) return;
    int c = idx & 63;
    int rest = idx >> 6;
    int w = rest % W1n; rest /= W1n;
    int h = rest % H1;
    int b = rest / H1;
    float out = 0.f;
    int vl2 = (lens[b] + 1) >> 1;
    if (h < vl2) {
        float a1 = b1[c], a2 = b2[c];
        #pragma unroll
        for (int r = 0; r < 3; ++r) {
            int t = 2 * h + r;
            if (t < Tn) {
                #pragma unroll
                for (int q = 0; q < 3; ++q) {
                    int f = 2 * w + q;
                    if (f < Fn) {
                        float v = in[(b * Tn + t) * Fn + f];
                        int wi = (r * 3 + q) * 64 + c;
                        a1 = fmaf(v, w1[wi], a1);
                        a2 = fmaf(v, w2[wi], a2);
                    }
                }
            }
        }
        out = fmaxf(a1, a2);
    }
    x1[idx] = f2bf(out);
}

// ---------------------------------------------------------------- K2: conv1 via MFMA implicit GEMM
// M=81920 (b,h,w), N=128 (n'=2c+s interleaved w1/w2), K=576. 128x128 tile/block.
__global__ void __launch_bounds__(256) k_conv1(
        const u16* __restrict__ x1, const u16* __restrict__ wt,
        const float* __restrict__ biasi, const int* __restrict__ lens,
        u16* __restrict__ x2) {
    constexpr int LD = 40;                      // LDS row stride in bf16 (80B: 16B-aligned, 2-way banks)
    __shared__ u16 Al[2][128 * LD];             // 2 x 10240 B
    __shared__ u16 Bl[2][128 * LD];
    __shared__ float bs_lds[128];

    int tid = threadIdx.x;
    int m0 = blockIdx.x * 128;
    int b = m0 / 10240;                         // 10240 | 128 -> uniform per block
    int vl4 = (lens[b] + 3) >> 2;

    if (tid < 128) bs_lds[tid] = biasi[tid];

    // staging: thread t -> row srow, 16-bf16 half shalf of the 32-wide k-chunk
    int srow = tid >> 1;
    int shalf = tid & 1;
    int am = m0 + srow;
    int aw = am % 20;
    int ah = (am / 20) % 512;
    const u16* abase = x1 + (((size_t)b * 1024 + 2 * ah) * 40 + 2 * aw) * 64;
    const u16* bbase = wt + srow * KC1;

    const uint4 uz = make_uint4(0, 0, 0, 0);
    uint4 na0, na1, nb0, nb1;
    {   // prefetch chunk 0: r=0,q=0,ci0=0 (always in-bounds)
        const u16* ap = abase + shalf * 16;
        na0 = *(const uint4*)(ap);
        na1 = *(const uint4*)(ap + 8);
        const u16* bp = bbase + shalf * 16;
        nb0 = *(const uint4*)(bp);
        nb1 = *(const uint4*)(bp + 8);
    }
    {
        u16* awp = &Al[0][srow * LD + shalf * 16];
        *(uint4*)awp = na0; *(uint4*)(awp + 8) = na1;
        u16* bwp = &Bl[0][srow * LD + shalf * 16];
        *(uint4*)bwp = nb0; *(uint4*)(bwp + 8) = nb1;
    }
    __syncthreads();

    int lane = tid & 63;
    int wid = tid >> 6;
    int mw = wid & 1, nw = wid >> 1;            // 2x2 wave grid (64m x 64n each)
    int frow = lane & 15;
    int koff = (lane >> 4) * 8;

    f32x4 acc[4][4] = {};
    int buf = 0;

    #pragma unroll
    for (int kc = 0; kc < 18; ++kc) {
        if (kc < 17) {
            int kn = kc + 1;
            int rq = kn >> 1, ci0 = (kn & 1) * 32;
            int r = rq / 3, q = rq - 3 * r;
            bool v = (2 * ah + r < 1024) && (2 * aw + q < 40);
            const u16* ap = abase + (r * 40 + q) * 64 + ci0 + shalf * 16;
            na0 = v ? *(const uint4*)(ap) : uz;
            na1 = v ? *(const uint4*)(ap + 8) : uz;
            const u16* bp = bbase + kn * 32 + shalf * 16;
            nb0 = *(const uint4*)(bp);
            nb1 = *(const uint4*)(bp + 8);
        }
        const u16* Ar = &Al[buf][(mw * 64 + frow) * LD + koff];
        const u16* Br = &Bl[buf][(nw * 64 + frow) * LD + koff];
        short8 af[4], bfr[4];
        #pragma unroll
        for (int s = 0; s < 4; ++s) {
            af[s]  = *(const short8*)(Ar + s * 16 * LD);
            bfr[s] = *(const short8*)(Br + s * 16 * LD);
        }
        #pragma unroll
        for (int sm = 0; sm < 4; ++sm)
            #pragma unroll
            for (int sn = 0; sn < 4; ++sn)
                acc[sm][sn] = __builtin_amdgcn_mfma_f32_16x16x32_bf16(
                    af[sm], bfr[sn], acc[sm][sn], 0, 0, 0);
        if (kc < 17) {
            buf ^= 1;
            u16* awp = &Al[buf][srow * LD + shalf * 16];
            *(uint4*)awp = na0; *(uint4*)(awp + 8) = na1;
            u16* bwp = &Bl[buf][srow * LD + shalf * 16];
            *(uint4*)bwp = nb0; *(uint4*)(bwp + 8) = nb1;
            __syncthreads();
        }
    }

    // epilogue: +bias, maxout over n'-pairs (DPP xor1), mask, store bf16
    int orow = (lane >> 4) * 4;
    int ncol = lane & 15;
    #pragma unroll
    for (int sm = 0; sm < 4; ++sm) {
        #pragma unroll
        for (int sn = 0; sn < 4; ++sn) {
            int np = nw * 64 + sn * 16 + ncol;
            float bia = bs_lds[np];
            #pragma unroll
            for (int r = 0; r < 4; ++r) {
                float v = acc[sm][sn][r] + bia;
                float o = fmaxf(v, dpp_mov<0xB1>(v));   // pair n' xor 1
                if (!(lane & 1)) {
                    int gm = m0 + mw * 64 + sm * 16 + orow + r;
                    int w = gm % 20;
                    int h = (gm / 20) % 512;
                    float res = (h >= vl4) ? 0.f : o;
                    x2[((size_t)(b * 512 + h) * 20 + w) * 64 + (np >> 1)] = f2bf(res);
                }
            }
        }
    }
}

// ---------------------------------------------------------------- K3a: projection
__global__ void __launch_bounds__(256) k_proj(
        const u16* __restrict__ x2, const float* __restrict__ pw,
        const float* __restrict__ pb, float* __restrict__ proj) {
    int bs = blockIdx.x;
    int tid = threadIdx.x;
    int o = tid & 31, part = tid >> 5;      // 8 parts of 160
    const u16* row = &x2[(size_t)bs * PK];
    float acc = 0.f;
    int k0 = part * 160;
    #pragma unroll 8
    for (int k = 0; k < 160; ++k)
        acc = fmaf(bf2f(row[k0 + k]), pw[(k0 + k) * 32 + o], acc);
    __shared__ float red[256];
    red[tid] = acc;
    __syncthreads();
    if (tid < 32) {
        float s = 0.f;
        #pragma unroll
        for (int p = 0; p < 8; ++p) s += red[p * 32 + tid];
        proj[bs * 32 + tid] = s + pb[tid];
    }
}

// ---------------------------------------------------------------- K3b: enc conv + mask + squash + LN
__global__ void __launch_bounds__(256) k_enc(
        const float* __restrict__ proj,
        const float* __restrict__ ew1, const float* __restrict__ eb1,
        const float* __restrict__ ew2, const float* __restrict__ eb2,
        const int* __restrict__ lens, float* __restrict__ emb0) {
    int bs = blockIdx.x;
    int s = bs & (Sn - 1);
    int b = bs >> 9;
    int tid = threadIdx.x;
    __shared__ float rows[3][32];
    __shared__ float red[8];
    if (tid < 96) {
        int r = tid >> 5, n = tid & 31;
        int sr = s - 1 + r;
        rows[r][n] = (sr >= 0 && sr < Sn) ? proj[(b * Sn + sr) * 32 + n] : 0.f;
    }
    __syncthreads();

    int n = tid >> 3, d = tid & 7;
    float a1 = eb1[d], a2 = eb2[d];
    #pragma unroll
    for (int r = 0; r < 3; ++r) {
        #pragma unroll
        for (int q = 0; q < 3; ++q) {
            int nn = n - 1 + q;
            if (nn >= 0 && nn < 32) {
                float v = rows[r][nn];
                int wi = (r * 3 + q) * 8 + d;
                a1 = fmaf(v, ew1[wi], a1);
                a2 = fmaf(v, ew2[wi], a2);
            }
        }
    }
    float x = fmaxf(a1, a2);
    int vl4 = (lens[b] + 3) >> 2;
    if (s >= vl4) x = 0.f;

    float sq = sum8(x * x);
    x = x * (sq / (1.f + sq) * rsqrtf(sq + 1e-6f));

    float2 ss = block_sum2(x, x * x, tid, red);
    float mu = ss.x * (1.f / 256.f);
    float var = ss.y * (1.f / 256.f) - mu * mu;
    emb0[bs * 256 + tid] = (x - mu) * rsqrtf(var + 1e-3f);
}

// ---------------------------------------------------------------- K4: caps layer 0
__global__ void __launch_bounds__(256) k_caps0(
        const float* __restrict__ embin, const u16* __restrict__ W0,
        const float* __restrict__ B0, float* __restrict__ embout) {
    int bs = blockIdx.x;
    int s = bs & (Sn - 1);
    int b = bs >> 9;
    int tid = threadIdx.x;
    int o = tid >> 3;

    __shared__ __align__(16) float win[I0 * 8];
    __shared__ float blog[I0 * 33];
    __shared__ float cct[O0 * CP];
    __shared__ float red[8];

    for (int i = tid; i < I0 * 8; i += 256) {
        int wj = i >> 8;
        int sr = s + wj - 1;
        win[i] = (sr >= 0 && sr < Sn) ? embin[(b * Sn + sr) * 256 + (i & 255)] : 0.f;
    }
    for (int i = tid; i < I0 * 33; i += 256) blog[i] = 0.f;
    __syncthreads();

    float u_reg[I0];
    {
        const uint4* Wv = (const uint4*)W0;
        const float4* w4 = (const float4*)win;
        #pragma unroll
        for (int i = 0; i < I0; ++i) {
            uint4 wv = Wv[i * 256 + tid];
            float4 wa = w4[i * 2], wb = w4[i * 2 + 1];
            float acc = B0[i * 256 + tid];
            acc = fmaf(__uint_as_float(wv.x << 16),         wa.x, acc);
            acc = fmaf(__uint_as_float(wv.x & 0xffff0000u), wa.y, acc);
            acc = fmaf(__uint_as_float(wv.y << 16),         wa.z, acc);
            acc = fmaf(__uint_as_float(wv.y & 0xffff0000u), wa.w, acc);
            acc = fmaf(__uint_as_float(wv.z << 16),         wb.x, acc);
            acc = fmaf(__uint_as_float(wv.z & 0xffff0000u), wb.y, acc);
            acc = fmaf(__uint_as_float(wv.w << 16),         wb.z, acc);
            acc = fmaf(__uint_as_float(wv.w & 0xffff0000u), wb.w, acc);
            u_reg[i] = acc;
        }
    }

    float vval = 0.f;
    for (int it = 0; it < 3; ++it) {
        if (tid < I0) {
            float m = -1e30f;
            for (int oo = 0; oo < O0; ++oo) m = fmaxf(m, blog[tid * 33 + oo]);
            float ssum = 0.f;
            for (int oo = 0; oo < O0; ++oo) ssum += __expf(blog[tid * 33 + oo] - m);
            float inv = __builtin_amdgcn_rcpf(ssum);
            for (int oo = 0; oo < O0; ++oo)
                cct[oo * CP + tid] = __expf(blog[tid * 33 + oo] - m) * inv;
        }
        __syncthreads();
        float sv = 0.f;
        {
            const float* cr = &cct[o * CP];
            #pragma unroll
            for (int i = 0; i < I0; ++i) sv = fmaf(cr[i], u_reg[i], sv);
        }
        float sq = sum8(sv * sv);
        vval = sv * (sq / (1.f + sq) * rsqrtf(sq + 1e-6f));
        if (it < 2) {
            #pragma unroll
            for (int i = 0; i < I0; ++i) {
                float p = sum8(u_reg[i] * vval);
                if ((tid & 7) == 0) blog[i * 33 + o] += p;
            }
            __syncthreads();
        }
    }

    float2 ss = block_sum2(vval, vval * vval, tid, red);
    float mu = ss.x * (1.f / 256.f);
    float var = ss.y * (1.f / 256.f) - mu * mu;
    embout[bs * 256 + tid] = (vval - mu) * rsqrtf(var + 1e-3f);
}

// ---------------------------------------------------------------- K5: caps layer 1 + epilogue
__global__ void __launch_bounds__(256) k_caps1(
        const float* __restrict__ embin, const u16* __restrict__ W1,
        const float* __restrict__ B1, float* __restrict__ outp) {
    int bs = blockIdx.x;
    int s = bs & (Sn - 1);
    int b = bs >> 9;
    int tid = threadIdx.x;
    int o = tid >> 3, d = tid & 7;
    bool valid = (o < O1);
    int oc = valid ? o : (O1 - 1);
    int ocd = oc * 8 + d;

    __shared__ __align__(16) float win[I0 * 8];
    __shared__ float blog[I0 * 33];
    __shared__ float cct[O1 * CP];
    __shared__ float red[8];
    __shared__ float lenb[O1];
    __shared__ float mv2[2];

    for (int i = tid; i < I0 * 8; i += 256) {
        int wj = i >> 8;
        int sr = s + wj - 1;
        win[i] = (sr >= 0 && sr < Sn) ? embin[(b * Sn + sr) * 256 + (i & 255)] : 0.f;
    }
    for (int i = tid; i < I0 * 33; i += 256) blog[i] = 0.f;
    __syncthreads();

    float u_reg[I0];
    {
        const uint4* Wv = (const uint4*)W1;
        const float4* w4 = (const float4*)win;
        #pragma unroll
        for (int i = 0; i < I0; ++i) {
            uint4 wv = Wv[i * 248 + ocd];
            float4 wa = w4[i * 2], wb = w4[i * 2 + 1];
            float acc = B1[i * 248 + ocd];
            acc = fmaf(__uint_as_float(wv.x << 16),         wa.x, acc);
            acc = fmaf(__uint_as_float(wv.x & 0xffff0000u), wa.y, acc);
            acc = fmaf(__uint_as_float(wv.y << 16),         wa.z, acc);
            acc = fmaf(__uint_as_float(wv.y & 0xffff0000u), wa.w, acc);
            acc = fmaf(__uint_as_float(wv.z << 16),         wb.x, acc);
            acc = fmaf(__uint_as_float(wv.z & 0xffff0000u), wb.y, acc);
            acc = fmaf(__uint_as_float(wv.w << 16),         wb.z, acc);
            acc = fmaf(__uint_as_float(wv.w & 0xffff0000u), wb.w, acc);
            u_reg[i] = acc;
        }
    }

    float vval = 0.f;
    for (int it = 0; it < 3; ++it) {
        if (tid < I0) {
            float m = -1e30f;
            for (int oo = 0; oo < O1; ++oo) {
                float lv = blog[tid * 33 + oo] + (oo == 0 ? -1e9f : 0.f);
                m = fmaxf(m, lv);
            }
            float ssum = 0.f;
            for (int oo = 0; oo < O1; ++oo) {
                float lv = blog[tid * 33 + oo] + (oo == 0 ? -1e9f : 0.f);
                ssum += __expf(lv - m);
            }
            float inv = __builtin_amdgcn_rcpf(ssum);
            for (int oo = 0; oo < O1; ++oo) {
                float lv = blog[tid * 33 + oo] + (oo == 0 ? -1e9f : 0.f);
                cct[oo * CP + tid] = __expf(lv - m) * inv;
            }
        }
        __syncthreads();
        float sv = 0.f;
        {
            const float* cr = &cct[oc * CP];
            #pragma unroll
            for (int i = 0; i < I0; ++i) sv = fmaf(cr[i], u_reg[i], sv);
        }
        float sq = sum8(sv * sv);
        vval = sv * (sq / (1.f + sq) * rsqrtf(sq + 1e-6f));
        if (!valid) vval = 0.f;
        if (it < 2) {
            #pragma unroll
            for (int i = 0; i < I0; ++i) {
                float p = sum8(u_reg[i] * vval);
                if ((tid & 7) == 0 && valid) blog[i * 33 + o] += p;
            }
            __syncthreads();
        }
    }

    float2 ss = block_sum2(vval, vval * vval, tid, red);
    float mu = ss.x * (1.f / 248.f);
    float var = ss.y * (1.f / 248.f) - mu * mu;
    float y = (vval - mu) * rsqrtf(var + 1e-3f);

    float sq = sum8(y * y);
    if (valid && (tid & 7) == 0) lenb[o] = sqrtf(sq + 1e-6f);
    __syncthreads();

    if (tid == 0) {
        float s1 = 0.f, s2 = 0.f;
        for (int oo = 0; oo < O1; ++oo) { float t = lenb[oo]; s1 += t; s2 += t * t; }
        float m2 = s1 / 31.f;
        mv2[0] = m2;
        mv2[1] = rsqrtf(s2 / 31.f - m2 * m2 + 1e-3f);
    }
    __syncthreads();
    if (tid < O1)
        outp[(size_t)bs * O1 + tid] = (lenb[tid] - mv2[0]) * mv2[1];
}

// ---------------------------------------------------------------- launch
extern "C" void kernel_launch(void* const* d_in, const int* in_sizes, int n_in,
                              void* d_out, int out_size, void* d_ws, size_t ws_size,
                              hipStream_t stream) {
    const float* inputs = (const float*)d_in[0];
    const float* c0w1 = (const float*)d_in[1];
    const float* c0b1 = (const float*)d_in[2];
    const float* c0w2 = (const float*)d_in[3];
    const float* c0b2 = (const float*)d_in[4];
    const float* c1w1 = (const float*)d_in[5];
    const float* c1b1 = (const float*)d_in[6];
    const float* c1w2 = (const float*)d_in[7];
    const float* c1b2 = (const float*)d_in[8];
    const float* pw   = (const float*)d_in[9];
    const float* pb   = (const float*)d_in[10];
    const float* ew1  = (const float*)d_in[11];
    const float* eb1  = (const float*)d_in[12];
    const float* ew2  = (const float*)d_in[13];
    const float* eb2  = (const float*)d_in[14];
    const float* W0   = (const float*)d_in[15];
    const float* B0   = (const float*)d_in[16];
    const float* W1   = (const float*)d_in[17];
    const float* B1   = (const float*)d_in[18];
    const int* lens = (const int*)d_in[19];

    char* ws = (char*)d_ws;
    u16*   x1    = (u16*)(ws);                       // 41,943,040 B
    u16*   x2    = (u16*)(ws + 41943040);            // 10,485,760 B (bf16)
    float* proj  = (float*)(ws + 52428800);          //    524,288 B
    float* emb0  = (float*)(ws + 52953088);          //  4,194,304 B
    float* emb1  = (float*)(ws + 57147392);          //  4,194,304 B
    u16*   W0b   = (u16*)(ws + 61341696);            //    393,216 B
    u16*   W1b   = (u16*)(ws + 61734912);            //    380,928 B
    u16*   wt    = (u16*)(ws + 62115840);            //    147,456 B
    float* biasi = (float*)(ws + 62263296);          //        512 B (end ~62.3 MB)

    k_prep<<<(NW0 + 255) / 256, 256, 0, stream>>>(
        W0, W1, c1w1, c1b1, c1w2, c1b2, W0b, W1b, wt, biasi);
    k_conv0<<<(Bn * H1 * W1n * NF) / 256, 256, 0, stream>>>(
        inputs, c0w1, c0b1, c0w2, c0b2, lens, x1);
    k_conv1<<<640, 256, 0, stream>>>(x1, wt, biasi, lens, x2);
    k_proj<<<Bn * Sn, 256, 0, stream>>>(x2, pw, pb, proj);
    k_enc<<<Bn * Sn, 256, 0, stream>>>(proj, ew1, eb1, ew2, eb2, lens, emb0);
    k_caps0<<<Bn * Sn, 256, 0, stream>>>(emb0, W0b, B0, emb1);
    k_caps1<<<Bn * Sn, 256, 0, stream>>>(emb1, W1b, B1, (float*)d_out);
}